// Round 2
// baseline (93.520 us; speedup 1.0000x reference)
//
#include <hip/hip_runtime.h>

// Problem: out[n,s,d] = (x[n,s,d] + pe(s,d)) * mask[n,s,d]
//   pe(s,d) = sin(s * f(d))  if d even
//           = cos(s * f(d))  if d odd
//   f(d) = exp( (d - d%2) * (-ln(10000)/D) )
// N=8, S=4096, D=1024, all fp32. Memory-bound: 3 x 128 MB streams.

constexpr int N = 8;
constexpr int S = 4096;
constexpr int D = 1024;
constexpr int DV = D / 4;                 // float4 granularity along D (=256)
constexpr int SD4 = S * DV;               // float4 elements per batch slice

__global__ __launch_bounds__(256)
void PositionalEncoding_78855599554887_kernel(const float4* __restrict__ x,
                                              const float4* __restrict__ mask,
                                              float4* __restrict__ out) {
    const int t = blockIdx.x * blockDim.x + threadIdx.x;   // [0, S*DV)
    if (t >= SD4) return;

    const int d4 = t & (DV - 1);          // which float4 along D, [0,256)
    const int s  = t >> 8;                // t / DV   (DV = 256)  -- was the bug
    const float db = (float)(d4 * 4);     // even base index (d4*4 is even)
    const float c  = -logf(10000.0f) / (float)D;   // folded at compile time

    // float4 covers d = {4k, 4k+1, 4k+2, 4k+3}:
    //   lanes 0,1 share freq(4k)   -> (sin, cos)
    //   lanes 2,3 share freq(4k+2) -> (sin, cos)
    const float fs = (float)s;
    const float a0 = fs * expf(db * c);
    const float a1 = fs * expf((db + 2.0f) * c);
    float s0, c0, s1, c1;
    sincosf(a0, &s0, &c0);
    sincosf(a1, &s1, &c1);
    const float4 pe = make_float4(s0, c0, s1, c1);

#pragma unroll
    for (int n = 0; n < N; ++n) {
        const int idx = n * SD4 + t;
        const float4 xv = x[idx];
        const float4 mv = mask[idx];
        float4 o;
        o.x = (xv.x + pe.x) * mv.x;
        o.y = (xv.y + pe.y) * mv.y;
        o.z = (xv.z + pe.z) * mv.z;
        o.w = (xv.w + pe.w) * mv.w;
        out[idx] = o;
    }
}

extern "C" void kernel_launch(void* const* d_in, const int* in_sizes, int n_in,
                              void* d_out, int out_size, void* d_ws, size_t ws_size,
                              hipStream_t stream) {
    const float4* x    = (const float4*)d_in[0];
    const float4* mask = (const float4*)d_in[1];
    float4* out        = (float4*)d_out;

    const int threads = 256;
    const int blocks  = (SD4 + threads - 1) / threads;   // 4096 blocks
    PositionalEncoding_78855599554887_kernel<<<blocks, threads, 0, stream>>>(x, mask, out);
}

// Round 4
// 74.705 us; speedup vs baseline: 1.2518x; 1.2518x over previous
//
#include <hip/hip_runtime.h>

// out[n,s,d] = (x[n,s,d] + pe(s,d)) * mask[n,s,d]
//   pe(s,d) = sin(s*f(d)) if d even else cos(s*f(d)),  f(d)=10000^(-(d - d%2)/D)
// N=8, S=4096, D=1024 fp32. Memory-bound: 3 x 128 MB streams.
//
// R2 post-mortem: interleaved load/compute/store -> 32 VGPRs -> one load-pair
// in flight per wave -> latency-bound at 2.8 TB/s effective.
// R3/R4: issue all 16 loads up front (static-indexed arrays), trig under the
// load shadow, then compute + nontemporal stores (out never re-read; keep L3
// for the x+mask working set across graph replays).
// R4 fix: __builtin_nontemporal_store needs a NATIVE vector type, not
// HIP_vector_type -> use ext_vector_type(4) float throughout.

typedef float floatx4 __attribute__((ext_vector_type(4)));

constexpr int N = 8;
constexpr int S = 4096;
constexpr int D = 1024;
constexpr int DV = D / 4;                 // float4 per row (=256)
constexpr int SD4 = S * DV;               // float4 per batch slice

__global__ __launch_bounds__(256)
void PositionalEncoding_78855599554887_kernel(const floatx4* __restrict__ x,
                                              const floatx4* __restrict__ mask,
                                              floatx4* __restrict__ out) {
    const int t = blockIdx.x * blockDim.x + threadIdx.x;   // [0, SD4)

    // ---- issue ALL loads first: 16 outstanding dwordx4 per thread ----
    floatx4 xv[N], mv[N];
#pragma unroll
    for (int n = 0; n < N; ++n) xv[n] = x[n * SD4 + t];
#pragma unroll
    for (int n = 0; n < N; ++n) mv[n] = mask[n * SD4 + t];

    // ---- trig overlaps the load latency ----
    const int d4 = t & (DV - 1);          // float4 index along D
    const int s  = t >> 8;                // row index (t / DV)
    const float db = (float)(d4 * 4);     // even base d
    const float c  = -logf(10000.0f) / (float)D;   // compile-time constant
    const float fs = (float)s;
    const float a0 = fs * expf(db * c);
    const float a1 = fs * expf((db + 2.0f) * c);
    float s0, c0, s1, c1;
    sincosf(a0, &s0, &c0);
    sincosf(a1, &s1, &c1);
    floatx4 pe;
    pe.x = s0; pe.y = c0; pe.z = s1; pe.w = c1;

    // ---- compute + streaming stores ----
#pragma unroll
    for (int n = 0; n < N; ++n) {
        floatx4 o = (xv[n] + pe) * mv[n];
        __builtin_nontemporal_store(o, &out[n * SD4 + t]);
    }
}

extern "C" void kernel_launch(void* const* d_in, const int* in_sizes, int n_in,
                              void* d_out, int out_size, void* d_ws, size_t ws_size,
                              hipStream_t stream) {
    const floatx4* x    = (const floatx4*)d_in[0];
    const floatx4* mask = (const floatx4*)d_in[1];
    floatx4* out        = (floatx4*)d_out;

    const int threads = 256;
    const int blocks  = SD4 / threads;    // 4096 blocks, exact cover
    PositionalEncoding_78855599554887_kernel<<<blocks, threads, 0, stream>>>(x, mask, out);
}

// Round 5
// 62.302 us; speedup vs baseline: 1.5011x; 1.1991x over previous
//
#include <hip/hip_runtime.h>

// out[n,s,d] = (x[n,s,d] + pe(s,d)) * mask[n,s,d]
//   pe(s,d) = sin(s*f(d)) if d even else cos(s*f(d)),  f(d)=10000^(-(d - d%2)/D)
// N=8, S=4096, D=1024 fp32. Memory-bound: 3 x 128 MB streams.
//
// R4 post-mortem: batch-of-8 per thread = 24 concurrent address streams/wave,
// 3.4 TB/s real HBM (54% of copy ceiling). Compiler refused the loads-first
// register budget anyway (VGPR 44). Trig amortization unneeded (VALUBusy 3%).
// R5: copy-kernel shape — ONE float4 per thread, 3 streams/wave, pure TLP.
// Trig recomputed per thread (~70 wave-cycles vs ~300 memory cycles: still
// memory-bound). nt-store kept: out is write-once, spare L3 for inputs.

typedef float floatx4 __attribute__((ext_vector_type(4)));

constexpr int N = 8;
constexpr int S = 4096;
constexpr int D = 1024;
constexpr int DV = D / 4;                 // float4 per row (=256)
constexpr int SD4 = S * DV;               // float4 per batch slice (=2^20)
constexpr int TOTAL = N * SD4;            // 8M float4

__global__ __launch_bounds__(256)
void PositionalEncoding_78855599554887_kernel(const floatx4* __restrict__ x,
                                              const floatx4* __restrict__ mask,
                                              floatx4* __restrict__ out) {
    const int t = blockIdx.x * blockDim.x + threadIdx.x;   // [0, TOTAL)

    // decode (s, d4) — n is irrelevant to PE
    const int d4 = t & (DV - 1);              // float4 index along D
    const int s  = (t >> 8) & (S - 1);        // row index within slice

    const float db = (float)(d4 * 4);         // even base d
    const float c  = -logf(10000.0f) / (float)D;   // compile-time constant
    const float fs = (float)s;
    const float a0 = fs * expf(db * c);
    const float a1 = fs * expf((db + 2.0f) * c);
    float s0, c0, s1, c1;
    sincosf(a0, &s0, &c0);
    sincosf(a1, &s1, &c1);
    floatx4 pe;
    pe.x = s0; pe.y = c0; pe.z = s1; pe.w = c1;

    const floatx4 xv = x[t];
    const floatx4 mv = mask[t];
    floatx4 o = (xv + pe) * mv;
    __builtin_nontemporal_store(o, &out[t]);
}

extern "C" void kernel_launch(void* const* d_in, const int* in_sizes, int n_in,
                              void* d_out, int out_size, void* d_ws, size_t ws_size,
                              hipStream_t stream) {
    const floatx4* x    = (const floatx4*)d_in[0];
    const floatx4* mask = (const floatx4*)d_in[1];
    floatx4* out        = (floatx4*)d_out;

    const int threads = 256;
    const int blocks  = TOTAL / threads;      // 32768 blocks, exact cover
    PositionalEncoding_78855599554887_kernel<<<blocks, threads, 0, stream>>>(x, mask, out);
}

// Round 7
// 59.829 us; speedup vs baseline: 1.5631x; 1.0413x over previous
//
#include <hip/hip_runtime.h>
#include <math.h>

// out[n,s,d] = (x[n,s,d] + pe(s,d)) * mask[n,s,d]
//   pe(s,d) = sin(s*f(d)) if d even else cos(s*f(d)),  f(d)=10000^(-(d - d%2)/D)
// N=8, S=4096, D=1024 fp32. Memory-bound: 3 x 128 MB streams, no reuse.
//
// R5: copy-shape (1 float4/thread) -> 62.3 us, 6.46 TB/s aggregate vmem
// (>= m13 copy ceiling; L3 serves half the reads, nt-store spares L3).
// R6 FAILED: typo'd exponent constant (-0.0129746875 vs exact
// -log2(1e4)/1024 = -0.0129762816) -> angle error peaking ~0.18 rad at
// d~111,s=4095 -> absmax 0.219. Model matched the failure exactly.
// R7: same hw-transcendental structure, correct constant.
//   rev = s * exp2(d*c2 + k), c2=-log2(1e4)/D, k=-log2(2*pi)
//   fract -> v_sin_f32 / v_cos_f32 (input in revolutions, cdna4_isa §3).
// Residual error budget ~2e-3 << 0.1425 threshold.

typedef float floatx4 __attribute__((ext_vector_type(4)));

constexpr int N = 8;
constexpr int S = 4096;
constexpr int D = 1024;
constexpr int DV = D / 4;                 // float4 per row (=256)
constexpr int SD4 = S * DV;               // float4 per batch slice (=2^20)
constexpr int TOTAL = N * SD4;            // 8M float4

__device__ __forceinline__ float hw_sin_rev(float rev) {
    float fr = rev - floorf(rev);         // v_fract
    float r;
    asm("v_sin_f32 %0, %1" : "=v"(r) : "v"(fr));
    return r;                             // sin(2*pi*fr)
}
__device__ __forceinline__ float hw_cos_rev(float rev) {
    float fr = rev - floorf(rev);
    float r;
    asm("v_cos_f32 %0, %1" : "=v"(r) : "v"(fr));
    return r;                             // cos(2*pi*fr)
}

__global__ __launch_bounds__(256)
void PositionalEncoding_78855599554887_kernel(const floatx4* __restrict__ x,
                                              const floatx4* __restrict__ mask,
                                              floatx4* __restrict__ out) {
    const int t = blockIdx.x * blockDim.x + threadIdx.x;   // [0, TOTAL)

    // decode (s, d4) — n is irrelevant to PE
    const int d4 = t & (DV - 1);              // float4 index along D
    const int s  = (t >> 8) & (S - 1);        // row index within slice

    // rev(d) = s * 10000^(-d/D) / (2*pi) = s * exp2(d*c2 + k)
    const float c2 = -0.012976282f;           // -log2(10000)/1024 (exact to fp32)
    const float k  = -2.6514961f;             // -log2(2*pi)
    const float db = (float)(d4 * 4);         // even base d
    const float fs = (float)s;
    const float rev0 = fs * exp2f(db * c2 + k);            // d = 4k, 4k+1
    const float rev1 = fs * exp2f((db + 2.0f) * c2 + k);   // d = 4k+2, 4k+3

    floatx4 pe;
    pe.x = hw_sin_rev(rev0);
    pe.y = hw_cos_rev(rev0);
    pe.z = hw_sin_rev(rev1);
    pe.w = hw_cos_rev(rev1);

    const floatx4 xv = x[t];
    const floatx4 mv = mask[t];
    floatx4 o = (xv + pe) * mv;
    __builtin_nontemporal_store(o, &out[t]);
}

extern "C" void kernel_launch(void* const* d_in, const int* in_sizes, int n_in,
                              void* d_out, int out_size, void* d_ws, size_t ws_size,
                              hipStream_t stream) {
    const floatx4* x    = (const floatx4*)d_in[0];
    const floatx4* mask = (const floatx4*)d_in[1];
    floatx4* out        = (floatx4*)d_out;

    const int threads = 256;
    const int blocks  = TOTAL / threads;      // 32768 blocks, exact cover
    PositionalEncoding_78855599554887_kernel<<<blocks, threads, 0, stream>>>(x, mask, out);
}